// Round 1
// 3199.499 us; speedup vs baseline: 2.0285x; 2.0285x over previous
//
#include <hip/hip_runtime.h>
#include <cstdint>
#include <cstddef>

// ---- problem constants ----
#define TT 512
#define BB 256
#define HID 768
#define INDIM 129
#define INPAD 160
#define OUTD 128
#define KS_TOT 58   // 48 recurrent + 10 input ksteps of 16
#define KS_REC 48
#define XSTR 168    // xlds row stride (bf16)
#define GSTR 100    // gbuf row stride (f32), 16B-aligned, conflict-light

typedef __attribute__((ext_vector_type(8))) short bf16x8;
typedef __attribute__((ext_vector_type(4))) float f32x4;
typedef __attribute__((ext_vector_type(16))) float f32x16;
typedef unsigned short u16;
typedef unsigned long long u64;

#define MFMA32(A, B, C) __builtin_amdgcn_mfma_f32_32x32x16_bf16(A, B, C, 0, 0, 0)
#define ZERO16 {0.f,0.f,0.f,0.f,0.f,0.f,0.f,0.f,0.f,0.f,0.f,0.f,0.f,0.f,0.f,0.f}

__device__ __forceinline__ u16 f2bf(float f) {
  union { float f; unsigned u; } v; v.f = f;
  unsigned u = v.u;
  u += 0x7fffu + ((u >> 16) & 1u);   // RNE
  return (u16)(u >> 16);
}
__device__ __forceinline__ float sigm(float x) { return 1.0f / (1.0f + __expf(-x)); }
__device__ __forceinline__ float tanh_fast(float x) { return 2.0f / (1.0f + __expf(-2.0f * x)) - 1.0f; }

// ---------------- prep ----------------
__global__ __launch_bounds__(256) void prep_kernel(
    const float* __restrict__ W_ih, const float* __restrict__ W_hh,
    const float* __restrict__ b_ih, const float* __restrict__ b_hh,
    const float* __restrict__ W_dec, const float* __restrict__ b_dec,
    u16* __restrict__ Wpack, u16* __restrict__ Wdpack,
    float* __restrict__ biasg, u16* __restrict__ h0,
    unsigned* __restrict__ flags, float* __restrict__ out) {
  const int stride = blockDim.x * gridDim.x;
  const int i0 = blockIdx.x * blockDim.x + threadIdx.x;

  // Wpack[ct][nt][ks][lane][8]: B-frag for mfma_32x32x16 (n=lane&31, k=(lane>>5)*8+jj)
  for (int i = i0; i < 32 * 3 * KS_TOT * 512; i += stride) {
    int jj = i & 7, lane = (i >> 3) & 63, r = i >> 9;
    int ks = r % KS_TOT; int r2 = r / KS_TOT;
    int nt = r2 % 3, ct = r2 / 3;
    int p = nt * 32 + (lane & 31);          // packed gate-col 0..95
    int g = p / 24, j = p - g * 24;
    int row = g * HID + ct * 24 + j;        // W gate-row
    int kh = (lane >> 5) * 8 + jj;
    float v;
    if (ks < KS_REC) v = W_hh[(size_t)row * HID + ks * 16 + kh];
    else { int d = (ks - KS_REC) * 16 + kh; v = (d < INDIM) ? W_ih[(size_t)row * INDIM + d] : 0.f; }
    Wpack[i] = f2bf(v);
  }
  // Wdpack[ont][ks][lane][8]
  for (int i = i0; i < 4 * 48 * 512; i += stride) {
    int jj = i & 7, lane = (i >> 3) & 63, r = i >> 9;
    int ks = r % 48, nt = r / 48;
    int orow = nt * 32 + (lane & 31);
    int k = ks * 16 + (lane >> 5) * 8 + jj;
    Wdpack[i] = f2bf(W_dec[(size_t)orow * HID + k]);
  }
  for (int i = i0; i < 4 * HID; i += stride) biasg[i] = b_ih[i] + b_hh[i];
  for (int i = i0; i < BB * HID; i += stride) h0[i] = (u16)0;
  for (int i = i0; i < 256; i += stride) flags[i] = 0u;
  // out pre-init with decoder bias (decode K-split accumulates via atomicAdd)
  for (int i = i0; i < 256 * BB * OUTD; i += stride) out[i] = b_dec[i & (OUTD - 1)];
}

// ---------------- persistent LSTM ----------------
// Full-group wait (tail only)
__device__ __forceinline__ void waitflags(unsigned* fl, unsigned target, int lane) {
  for (;;) {
    unsigned v = __hip_atomic_load(&fl[lane & 31], __ATOMIC_RELAXED, __HIP_MEMORY_SCOPE_AGENT);
    if (__all((int)(v >= target))) break;
    __builtin_amdgcn_s_sleep(1);
  }
}
// Per-wave wait: wave w only consumes h cols [w*192, w*192+192) produced by
// ct = 8w..8w+7 of its batch group -> wait on just those 8 flags.
__device__ __forceinline__ void waitflags8(unsigned* fl8, unsigned target, int lane) {
  for (;;) {
    unsigned v = __hip_atomic_load(&fl8[lane & 7], __ATOMIC_RELAXED, __HIP_MEMORY_SCOPE_AGENT);
    if (__all((int)(v >= target))) break;
    __builtin_amdgcn_s_sleep(1);
  }
}

// Direct-to-register device-coherent 16B load of an MFMA A-frag.
// sc0 sc1 = bypass L1+L2, read at LLC (same bits the compiler emits for
// agent-scope relaxed atomic loads; producer stores are sc0 sc1 write-through
// and are vmcnt(0)-drained at B3 before the flag store).
#define HLOAD(i, off) asm volatile( \
    "global_load_dwordx4 %0, %1, off offset:" #off " sc0 sc1" \
    : "=v"(hreg[i]) : "v"(hrow) : "memory")
#define VMWAIT(n) do { asm volatile("s_waitcnt vmcnt(" #n ")" ::: "memory"); \
    __builtin_amdgcn_sched_barrier(0); } while (0)

__global__ __launch_bounds__(256, 1) void lstm_persist(
    const float* __restrict__ seq, const u16* __restrict__ Wpack,
    const u16* __restrict__ Wdpack, const float* __restrict__ biasg,
    u16* __restrict__ hb0, u16* __restrict__ hb1,
    unsigned* __restrict__ flags, float* __restrict__ out) {
  __shared__ float gbuf[4][32 * GSTR];   // 51,200 B: per-wave gate partials
  __shared__ u16 xlds[32 * XSTR];        // 10,752 B: x_s tile (bf16, zero-padded K)
  __shared__ float biasl[96];            //   total ~62 KB (hstage eliminated)

  const int tid = threadIdx.x;
  const int w = tid >> 6;
  const int lane = tid & 63;
  const int l5 = lane & 31;
  const int hi = lane >> 5;
  const int bid = blockIdx.x;
  const int bt = bid >> 5;               // 0..7  batch tile (32 rows)
  const int ct = bid & 31;               // 0..31 h-col tile (24 h-cols / 96 gate-cols)
  const int b0 = bt * 32;
  unsigned* fl = flags + bt * 32;

  // one-time LDS init
  for (int i = tid; i < 32 * 31; i += 256) {      // zero x pad cols 129..159
    int r = i / 31, d = INDIM + i - r * 31;
    xlds[r * XSTR + d] = (u16)0;
  }
  if (tid < 96) biasl[tid] = biasg[(tid / 24) * HID + ct * 24 + (tid % 24)];

  // ---- recurrent-B fragments in registers: wave w owns rec ksteps w*12..w*12+11 ----
  bf16x8 Breg[3][12];
  #pragma unroll
  for (int t = 0; t < 12; ++t)
    #pragma unroll
    for (int nt = 0; nt < 3; ++nt)
      Breg[nt][t] = *(const bf16x8*)(Wpack +
          (((size_t)(ct * 3 + nt)) * KS_TOT + (w * 12 + t)) * 512 + (size_t)lane * 8);

  const int icnt = (w < 2) ? 3 : 2;              // input ksteps: 3/3/2/2
  const int ioff = (w <= 2) ? w * 3 : 8;
  // input-B fragments in registers too (read every step otherwise)
  bf16x8 Bireg[3][3] = {};
  #pragma unroll
  for (int u = 0; u < 3; ++u)
    if (u < icnt) {
      #pragma unroll
      for (int nt = 0; nt < 3; ++nt)
        Bireg[u][nt] = *(const bf16x8*)(Wpack +
            (((size_t)(ct * 3 + nt)) * KS_TOT + KS_REC + ioff + u) * 512 + (size_t)lane * 8);
    }

  // stage x_0
  {
    const float* xs = seq + (size_t)b0 * INDIM;
    for (int i = tid; i < 32 * INDIM; i += 256) {
      int r = i / INDIM, d = i - r * INDIM;
      xlds[r * XSTR + d] = f2bf(xs[i]);
    }
  }

  // cell state: thread-private (threads 0..191 own (row=tid/6, colgrp=tid%6) forever)
  float creg[4] = {0.f, 0.f, 0.f, 0.f};
  const int cr = tid / 6, cg = tid - (tid / 6) * 6;
  __syncthreads();   // x_0 + pads + biasl ready

  for (int s = 0; s < TT; ++s) {
    const u16* hbprev = (s & 1) ? hb1 : hb0;
    u16* hbnext       = (s & 1) ? hb0 : hb1;

    // ---- input projection first: no h dependency, overlaps producers finishing ----
    f32x16 acc[3] = {ZERO16, ZERO16, ZERO16};
    #pragma unroll
    for (int u = 0; u < 3; ++u)
      if (u < icnt) {
        int kk = ioff + u;
        bf16x8 a = *(const bf16x8*)(xlds + l5 * XSTR + kk * 16 + hi * 8);
        acc[0] = MFMA32(a, Bireg[u][0], acc[0]);
        acc[1] = MFMA32(a, Bireg[u][1], acc[1]);
        acc[2] = MFMA32(a, Bireg[u][2], acc[2]);
      }

    // ---- per-wave wait on this wave's 8 producers only ----
    waitflags8(fl + 8 * w, (unsigned)s, lane);

    // ---- h_{s-1} direct to registers: 12 x dwordx4, one LLC round-trip ----
    bf16x8 hreg[12];
    {
      const u64 hrow = (u64)(hbprev + (size_t)(b0 + l5) * HID + w * 192 + hi * 8);
      HLOAD(0, 0);   HLOAD(1, 32);  HLOAD(2, 64);  HLOAD(3, 96);
      HLOAD(4, 128); HLOAD(5, 160); HLOAD(6, 192); HLOAD(7, 224);
      HLOAD(8, 256); HLOAD(9, 288); HLOAD(10, 320); HLOAD(11, 352);
    }
    VMWAIT(6);          // oldest 6 loads (t=0..5) retired (in-order retirement)
    #pragma unroll
    for (int t = 0; t < 6; ++t) {
      acc[0] = MFMA32(hreg[t], Breg[0][t], acc[0]);
      acc[1] = MFMA32(hreg[t], Breg[1][t], acc[1]);
      acc[2] = MFMA32(hreg[t], Breg[2][t], acc[2]);
    }
    VMWAIT(0);
    #pragma unroll
    for (int t = 6; t < 12; ++t) {
      acc[0] = MFMA32(hreg[t], Breg[0][t], acc[0]);
      acc[1] = MFMA32(hreg[t], Breg[1][t], acc[1]);
      acc[2] = MFMA32(hreg[t], Breg[2][t], acc[2]);
    }

    // ---- write gate partials ----
    {
      float* gb = gbuf[w];
      #pragma unroll
      for (int nt = 0; nt < 3; ++nt)
        #pragma unroll
        for (int r = 0; r < 16; ++r) {
          int row = (r & 3) + 8 * (r >> 2) + 4 * hi;
          gb[row * GSTR + nt * 32 + l5] = acc[nt][r];
        }
    }

    // ---- prefetch x_{s+1} into registers (latency hides under B2 + cell) ----
    float xf[17];
    if (s + 1 < TT) {
      const float* xs = seq + ((size_t)(s + 1) * BB + b0) * INDIM;
      #pragma unroll
      for (int k = 0; k < 17; ++k) {
        int i = tid + k * 256;
        xf[k] = (i < 32 * INDIM) ? xs[i] : 0.f;
      }
    }
    __syncthreads();   // B2: partials ready; xlds readers of x_s all done

    // ---- cell update: threads 0..191, 4 cells each, c in registers ----
    if (tid < 192) {
      float gv4[4][4];
      #pragma unroll
      for (int g = 0; g < 4; ++g) {
        f32x4 v = *(f32x4*)&gbuf[0][cr * GSTR + g * 24 + cg * 4];
        #pragma unroll
        for (int w2 = 1; w2 < 4; ++w2)
          v += *(f32x4*)&gbuf[w2][cr * GSTR + g * 24 + cg * 4];
        #pragma unroll
        for (int e = 0; e < 4; ++e) gv4[g][e] = v[e] + biasl[g * 24 + cg * 4 + e];
      }
      u64 pack = 0;
      #pragma unroll
      for (int e = 0; e < 4; ++e) {
        float iv = sigm(gv4[0][e]), fv = sigm(gv4[1][e]);
        float gg = tanh_fast(gv4[2][e]), ov = sigm(gv4[3][e]);
        float cn = fv * creg[e] + iv * gg;
        creg[e] = cn;
        pack |= (u64)f2bf(ov * tanh_fast(cn)) << (16 * e);
      }
      __hip_atomic_store((u64*)hbnext + ((size_t)(b0 + cr) * HID + ct * 24 + cg * 4) / 4,
                         pack, __ATOMIC_RELAXED, __HIP_MEMORY_SCOPE_AGENT);
    }
    // ---- write x_{s+1} to xlds (single buffer: free after B2) ----
    if (s + 1 < TT) {
      #pragma unroll
      for (int k = 0; k < 17; ++k) {
        int i = tid + k * 256;
        if (i < 32 * INDIM) {
          int r = i / INDIM, d = i - r * INDIM;
          xlds[r * XSTR + d] = f2bf(xf[k]);
        }
      }
    }
    __syncthreads();   // B3: compiler emits s_waitcnt vmcnt(0) before s_barrier:
                       // all h stores (sc1 write-through) ACKED at the coherence
                       // point; also publishes xlds for next step's input MFMA.

    // Flag store is RELAXED: ordering vs the h stores is provided by B3's
    // vmcnt(0) drain. RELEASE would emit buffer_wbl2 (measured: 14.7us/step).
    if (tid == 0)
      __hip_atomic_store(&fl[ct], (unsigned)(s + 1), __ATOMIC_RELAXED, __HIP_MEMORY_SCOPE_AGENT);

    // ---- fused decode of h_{s-1} -> out[s-257]: REUSES hreg, zero extra h loads ----
    if (s >= 257 && ((ct >> 2) == ((s - 257) & 7))) {
      const int ont = ct & 3;
      f32x16 dacc = ZERO16;
      #pragma unroll
      for (int t = 0; t < 12; ++t) {
        int ks = w * 12 + t;
        bf16x8 b = *(const bf16x8*)(Wdpack + (((size_t)ont * 48 + ks) * 64 + lane) * 8);
        dacc = MFMA32(hreg[t], b, dacc);
      }
      float* ob = out + ((size_t)(s - 257) * BB + b0) * OUTD + ont * 32;
      #pragma unroll
      for (int r = 0; r < 16; ++r) {
        int row = (r & 3) + 8 * (r >> 2) + 4 * hi;
        atomicAdd(&ob[(size_t)row * OUTD + l5], dacc[r]);
      }
    }
  }

  // ---- tail: decode h_511 -> out[255] (duty group 7, reads hb0 directly) ----
  if ((ct >> 2) == 7) {
    waitflags(fl, (unsigned)TT, lane);
    const int ont = ct & 3;
    const u64* hq = (const u64*)hb0;
    f32x16 acc = ZERO16;
    #pragma unroll
    for (int t = 0; t < 12; ++t) {
      int ks = w * 12 + t;
      union { u64 q[2]; bf16x8 v; } a;
      size_t base = ((size_t)(b0 + l5) * HID + ks * 16 + hi * 8) / 4;
      a.q[0] = __hip_atomic_load(hq + base,     __ATOMIC_RELAXED, __HIP_MEMORY_SCOPE_AGENT);
      a.q[1] = __hip_atomic_load(hq + base + 1, __ATOMIC_RELAXED, __HIP_MEMORY_SCOPE_AGENT);
      bf16x8 b = *(const bf16x8*)(Wdpack + (((size_t)ont * 48 + ks) * 64 + lane) * 8);
      acc = MFMA32(a.v, b, acc);
    }
    float* ob = out + ((size_t)255 * BB + b0) * OUTD + ont * 32;
    #pragma unroll
    for (int r = 0; r < 16; ++r) {
      int row = (r & 3) + 8 * (r >> 2) + 4 * hi;
      atomicAdd(&ob[(size_t)row * OUTD + l5], acc[r]);
    }
  }
}

extern "C" void kernel_launch(void* const* d_in, const int* in_sizes, int n_in,
                              void* d_out, int out_size, void* d_ws, size_t ws_size,
                              hipStream_t stream) {
  (void)in_sizes; (void)n_in; (void)out_size; (void)ws_size;
  const float* seq   = (const float*)d_in[0];
  const float* W_ih  = (const float*)d_in[1];
  const float* W_hh  = (const float*)d_in[2];
  const float* b_ih  = (const float*)d_in[3];
  const float* b_hh  = (const float*)d_in[4];
  const float* W_dec = (const float*)d_in[5];
  const float* b_dec = (const float*)d_in[6];
  float* out = (float*)d_out;

  // workspace layout (~6.7 MB, all offsets 16B-aligned)
  u16* Wpack  = (u16*)d_ws;                         // 32*3*58*512 bf16 = 5,701,632 B
  u16* Wdpack = Wpack + 32 * 3 * KS_TOT * 512;      // 98,304 bf16
  u16* h0     = Wdpack + 4 * 48 * 512;              // 256*768 bf16
  u16* h1     = h0 + BB * HID;                      // 256*768 bf16
  float* biasg = (float*)(h1 + BB * HID);           // 3072 f32
  unsigned* flags = (unsigned*)(biasg + 4 * HID);   // 256 u32

  prep_kernel<<<2048, 256, 0, stream>>>(W_ih, W_hh, b_ih, b_hh, W_dec, b_dec,
                                        Wpack, Wdpack, biasg, h0, flags, out);
  lstm_persist<<<256, 256, 0, stream>>>(seq, Wpack, Wdpack, biasg,
                                        h0, h1, flags, out);
}

// Round 5
// 2883.872 us; speedup vs baseline: 2.2505x; 1.1094x over previous
//
#include <hip/hip_runtime.h>
#include <cstdint>
#include <cstddef>

// ---- problem constants ----
#define TT 512
#define BB 256
#define HID 768
#define INDIM 129
#define OUTD 128
#define KS_TOT 58   // 48 recurrent + 10 input ksteps of 16
#define KS_REC 48
#define XSTR 168    // xlds row stride (bf16)
#define GSTR 100    // gbuf row stride (f32), 16B-aligned

typedef __attribute__((ext_vector_type(8))) short bf16x8;
typedef __attribute__((ext_vector_type(4))) float f32x4;
typedef __attribute__((ext_vector_type(16))) float f32x16;
typedef unsigned short u16;
typedef unsigned long long u64;

#define MFMA32(A, B, C) __builtin_amdgcn_mfma_f32_32x32x16_bf16(A, B, C, 0, 0, 0)
#define ZERO16 {0.f,0.f,0.f,0.f,0.f,0.f,0.f,0.f,0.f,0.f,0.f,0.f,0.f,0.f,0.f,0.f}

__device__ __forceinline__ u16 f2bf(float f) {
  union { float f; unsigned u; } v; v.f = f;
  unsigned u = v.u;
  u += 0x7fffu + ((u >> 16) & 1u);   // RNE
  return (u16)(u >> 16);
}
__device__ __forceinline__ float sigm(float x) { return 1.0f / (1.0f + __expf(-x)); }
__device__ __forceinline__ float tanh_fast(float x) { return 2.0f / (1.0f + __expf(-2.0f * x)) - 1.0f; }

// ---------------- prep ----------------
__global__ __launch_bounds__(256) void prep_kernel(
    const float* __restrict__ W_ih, const float* __restrict__ W_hh,
    const float* __restrict__ b_ih, const float* __restrict__ b_hh,
    const float* __restrict__ W_dec, const float* __restrict__ b_dec,
    u16* __restrict__ Wpack, u16* __restrict__ Wdpack,
    float* __restrict__ biasg, u16* __restrict__ h0,
    unsigned* __restrict__ flags, float* __restrict__ out) {
  const int stride = blockDim.x * gridDim.x;
  const int i0 = blockIdx.x * blockDim.x + threadIdx.x;

  // Wpack[ct][nt][ks][lane][8]: B-frag for mfma_32x32x16 (n=lane&31, k=(lane>>5)*8+jj)
  for (int i = i0; i < 32 * 3 * KS_TOT * 512; i += stride) {
    int jj = i & 7, lane = (i >> 3) & 63, r = i >> 9;
    int ks = r % KS_TOT; int r2 = r / KS_TOT;
    int nt = r2 % 3, ct = r2 / 3;
    int p = nt * 32 + (lane & 31);          // packed gate-col 0..95
    int g = p / 24, j = p - g * 24;
    int row = g * HID + ct * 24 + j;        // W gate-row
    int kh = (lane >> 5) * 8 + jj;
    float v;
    if (ks < KS_REC) v = W_hh[(size_t)row * HID + ks * 16 + kh];
    else { int d = (ks - KS_REC) * 16 + kh; v = (d < INDIM) ? W_ih[(size_t)row * INDIM + d] : 0.f; }
    Wpack[i] = f2bf(v);
  }
  // Wdpack[ont][ks][lane][8]
  for (int i = i0; i < 4 * 48 * 512; i += stride) {
    int jj = i & 7, lane = (i >> 3) & 63, r = i >> 9;
    int ks = r % 48, nt = r / 48;
    int orow = nt * 32 + (lane & 31);
    int k = ks * 16 + (lane >> 5) * 8 + jj;
    Wdpack[i] = f2bf(W_dec[(size_t)orow * HID + k]);
  }
  for (int i = i0; i < 4 * HID; i += stride) biasg[i] = b_ih[i] + b_hh[i];
  for (int i = i0; i < BB * HID; i += stride) h0[i] = (u16)0;
  // zero sflags(1024) + fflags(256)
  for (int i = i0; i < 1280; i += stride) flags[i] = 0u;
  // out pre-init with decoder bias (decode K-split accumulates via atomicAdd)
  for (int i = i0; i < 256 * BB * OUTD; i += stride) out[i] = b_dec[i & (OUTD - 1)];
}

// ---------------- persistent LSTM ----------------
// Full-group wait (tail only)
__device__ __forceinline__ void waitflags(unsigned* fl, unsigned target, int lane) {
  for (;;) {
    unsigned v = __hip_atomic_load(&fl[lane & 31], __ATOMIC_RELAXED, __HIP_MEMORY_SCOPE_AGENT);
    if (__all((int)(v >= target))) break;
    __builtin_amdgcn_s_sleep(1);
  }
}
// Poll load: fused issue+wait inside ONE asm block (safe: no async register
// lifetime visible to the compiler — the R1-proven pattern).
__device__ __forceinline__ unsigned flagld(const unsigned* p) {
  unsigned v; u64 a = (u64)p;
  asm volatile("global_load_dword %0, %1, off sc0 sc1\n\ts_waitcnt vmcnt(0)"
               : "=v"(v) : "v"(a) : "memory");
  return v;
}
__device__ __forceinline__ void stflag(unsigned* p, unsigned v) {
  u64 a = (u64)p;
  asm volatile("global_store_dword %0, %1, off sc0 sc1" :: "v"(a), "v"(v) : "memory");
}

// Direct-to-register device-coherent 16B loads of MFMA A-frags (R1-proven).
// hreg is consumed after VMWAIT within the SAME iteration — no backedge
// crossing of in-flight asm destinations (R3/R4 lesson).
#define HLD(i, off) asm volatile( \
    "global_load_dwordx4 %0, %1, off offset:" #off " sc0 sc1" \
    : "=v"(hreg[i]) : "v"(hrow) : "memory")
#define HLOADS() do { HLD(0,0); HLD(1,32); HLD(2,64); HLD(3,96); \
    HLD(4,128); HLD(5,160); HLD(6,192); HLD(7,224); \
    HLD(8,256); HLD(9,288); HLD(10,320); HLD(11,352); } while (0)

#define VMWAIT(n) do { asm volatile("s_waitcnt vmcnt(" #n ")" ::: "memory"); \
    __builtin_amdgcn_sched_barrier(0); } while (0)

__global__ __launch_bounds__(256, 1) void lstm_persist(
    const float* __restrict__ seq, const u16* __restrict__ Wpack,
    const u16* __restrict__ Wdpack, const float* __restrict__ biasg,
    u16* __restrict__ hb0, u16* __restrict__ hb1,
    unsigned* __restrict__ sflags, unsigned* __restrict__ fflags,
    float* __restrict__ out) {
  __shared__ float gbuf[4][32 * GSTR];   // 51,200 B
  __shared__ u16 xlds[32 * XSTR];        // 10,752 B
  __shared__ float biasl[96];

  const int tid = threadIdx.x;
  const int w = tid >> 6;
  const int lane = tid & 63;
  const int l5 = lane & 31;
  const int hi = lane >> 5;
  const int bid = blockIdx.x;
  const int bt = bid >> 5;               // 0..7  batch tile (32 rows)
  const int ct = bid & 31;               // 0..31 h-col tile (24 h-cols / 96 gate-cols)
  const int b0 = bt * 32;
  unsigned* sfl = sflags + bt * 128;     // [ct][4] per-cell-wave sub-flags
  unsigned* ffl = fflags + bt * 32;      // [ct] final flags (tail only)

  // one-time LDS init
  for (int i = tid; i < 32 * 31; i += 256) {      // zero x pad cols 129..159
    int r = i / 31, d = INDIM + i - r * 31;
    xlds[r * XSTR + d] = (u16)0;
  }
  if (tid < 96) biasl[tid] = biasg[(tid / 24) * HID + ct * 24 + (tid % 24)];

  // ---- recurrent-B fragments in registers: wave w owns rec ksteps w*12..w*12+11 ----
  bf16x8 Breg[3][12];
  #pragma unroll
  for (int t = 0; t < 12; ++t)
    #pragma unroll
    for (int nt = 0; nt < 3; ++nt)
      Breg[nt][t] = *(const bf16x8*)(Wpack +
          (((size_t)(ct * 3 + nt)) * KS_TOT + (w * 12 + t)) * 512 + (size_t)lane * 8);

  const int icnt = (w < 2) ? 3 : 2;              // input ksteps: 3/3/2/2
  const int ioff = (w <= 2) ? w * 3 : 8;
  bf16x8 Bireg[3][3] = {};
  #pragma unroll
  for (int u = 0; u < 3; ++u)
    if (u < icnt) {
      #pragma unroll
      for (int nt = 0; nt < 3; ++nt)
        Bireg[u][nt] = *(const bf16x8*)(Wpack +
            (((size_t)(ct * 3 + nt)) * KS_TOT + KS_REC + ioff + u) * 512 + (size_t)lane * 8);
    }

  // decoder B-fragments in registers (ont = ct&3 fixed per WG; in-loop + tail)
  bf16x8 Dreg[12];
  #pragma unroll
  for (int t = 0; t < 12; ++t)
    Dreg[t] = *(const bf16x8*)(Wdpack +
        (((size_t)(ct & 3) * 48 + w * 12 + t) * 64 + lane) * 8);

  // stage x_0
  {
    const float* xs = seq + (size_t)b0 * INDIM;
    for (int i = tid; i < 32 * INDIM; i += 256) {
      int r = i / INDIM, d = i - r * INDIM;
      xlds[r * XSTR + d] = f2bf(xs[i]);
    }
  }

  // cell state: thread-private (threads 0..191 own (row=tid/6, colgrp=tid%6) forever)
  float creg[4] = {0.f, 0.f, 0.f, 0.f};
  const int cr = tid / 6, cg = tid - (tid / 6) * 6;
  // wave w consumes h cols [w*192,+192) <- producers ct'=8w..8w+7, cell-waves 0..2:
  // lane<24 maps (producer p=lane/3, cell-wave ws=lane%3); lanes>=24 duplicate p=0,ws=0.
  const unsigned* sfp = sfl + ((lane < 24) ? ((8 * w + lane / 3) * 4 + (lane % 3))
                                           : (8 * w) * 4);

  __syncthreads();   // x_0 + pads + biasl ready

  for (int s = 0; s < TT; ++s) {
    const u16* hbprev = (s & 1) ? hb1 : hb0;
    u16* hbnext       = (s & 1) ? hb0 : hb1;

    // ---- poll FIRST (queue is empty: x/decode drained at B2/B3 last step) ----
    for (;;) {
      unsigned v = flagld(sfp);
      if (__all((int)(v >= (unsigned)s))) break;
      __builtin_amdgcn_s_sleep(1);
    }

    // ---- h_{s-1} direct to registers: issue immediately after flag confirm ----
    bf16x8 hreg[12];
    {
      const u64 hrow = (u64)(hbprev + (size_t)(b0 + l5) * HID + w * 192 + hi * 8);
      HLOADS();
    }

    // ---- input projection UNDER the h RT (independent of h; LDS + MFMA only) ----
    f32x16 acc[3] = {ZERO16, ZERO16, ZERO16};
    #pragma unroll
    for (int u = 0; u < 3; ++u)
      if (u < icnt) {
        int kk = ioff + u;
        bf16x8 a = *(const bf16x8*)(xlds + l5 * XSTR + kk * 16 + hi * 8);
        acc[0] = MFMA32(a, Bireg[u][0], acc[0]);
        acc[1] = MFMA32(a, Bireg[u][1], acc[1]);
        acc[2] = MFMA32(a, Bireg[u][2], acc[2]);
      }

    // ---- recurrent MFMA: queue is h-only -> simple counted waits ----
    VMWAIT(6);          // oldest 6 h loads retired (in-order retirement)
    #pragma unroll
    for (int t = 0; t < 6; ++t) {
      acc[0] = MFMA32(hreg[t], Breg[0][t], acc[0]);
      acc[1] = MFMA32(hreg[t], Breg[1][t], acc[1]);
      acc[2] = MFMA32(hreg[t], Breg[2][t], acc[2]);
    }
    VMWAIT(0);
    #pragma unroll
    for (int t = 6; t < 12; ++t) {
      acc[0] = MFMA32(hreg[t], Breg[0][t], acc[0]);
      acc[1] = MFMA32(hreg[t], Breg[1][t], acc[1]);
      acc[2] = MFMA32(hreg[t], Breg[2][t], acc[2]);
    }

    // ---- x_{s+1} prefetch issue AFTER h waits (drains at B2) ----
    float xf[17];
    if (s + 1 < TT) {
      const float* xs = seq + ((size_t)(s + 1) * BB + b0) * INDIM;
      #pragma unroll
      for (int k = 0; k < 17; ++k) {
        int i = tid + k * 256;
        xf[k] = (i < 32 * INDIM) ? xs[i] : 0.f;
      }
    }

    // ---- write gate partials ----
    {
      float* gbw = &gbuf[w][0];
      #pragma unroll
      for (int nt = 0; nt < 3; ++nt)
        #pragma unroll
        for (int r = 0; r < 16; ++r) {
          int row = (r & 3) + 8 * (r >> 2) + 4 * hi;
          gbw[row * GSTR + nt * 32 + l5] = acc[nt][r];
        }
    }

    __syncthreads();   // B2: partials ready; drains x loads; queue now empty

    // ---- cell update: threads 0..191 (waves 0..2), 4 cells each, c in regs.
    // Each cell wave drains ITS OWN h stores and posts its sub-flag BEFORE
    // the xlds write / decode / B3 — the handoff leaves the WG here. ----
    if (tid < 192) {
      float gv4[4][4];
      #pragma unroll
      for (int g = 0; g < 4; ++g) {
        f32x4 v = *(f32x4*)&gbuf[0][cr * GSTR + g * 24 + cg * 4];
        #pragma unroll
        for (int w2 = 1; w2 < 4; ++w2)
          v += *(f32x4*)&gbuf[w2][cr * GSTR + g * 24 + cg * 4];
        #pragma unroll
        for (int e = 0; e < 4; ++e) gv4[g][e] = v[e] + biasl[g * 24 + cg * 4 + e];
      }
      u64 pack = 0;
      #pragma unroll
      for (int e = 0; e < 4; ++e) {
        float iv = sigm(gv4[0][e]), fv2 = sigm(gv4[1][e]);
        float gg = tanh_fast(gv4[2][e]), ov = sigm(gv4[3][e]);
        float cn = fv2 * creg[e] + iv * gg;
        creg[e] = cn;
        pack |= (u64)f2bf(ov * tanh_fast(cn)) << (16 * e);
      }
      __hip_atomic_store((u64*)hbnext + ((size_t)(b0 + cr) * HID + ct * 24 + cg * 4) / 4,
                         pack, __ATOMIC_RELAXED, __HIP_MEMORY_SCOPE_AGENT);
      // queue holds ONLY this wave's h store (B2 drained everything else):
      // ack it at the coherence point, then post this wave's sub-flag.
      asm volatile("s_waitcnt vmcnt(0)" ::: "memory");
      __builtin_amdgcn_sched_barrier(0);
      if (lane == 0) stflag(sfl + ct * 4 + w, (unsigned)(s + 1));
    }

    // ---- write x_{s+1} to xlds (cell waves after their sub-flag; wave 3 now) ----
    if (s + 1 < TT) {
      #pragma unroll
      for (int k = 0; k < 17; ++k) {
        int i = tid + k * 256;
        if (i < 32 * INDIM) {
          int r = i / INDIM, d = i - r * INDIM;
          xlds[r * XSTR + d] = f2bf(xf[k]);
        }
      }
    }

    // ---- fused decode of h_{s-1} -> out[s-257]: post-sub-flag, so its
    // atomic ACKs drain in OUR B3, off the group handoff path ----
    if (s >= 257 && ((ct >> 2) == ((s - 257) & 7))) {
      const int ont = ct & 3;
      f32x16 dacc = ZERO16;
      #pragma unroll
      for (int t = 0; t < 12; ++t) dacc = MFMA32(hreg[t], Dreg[t], dacc);
      float* ob = out + ((size_t)(s - 257) * BB + b0) * OUTD + ont * 32;
      #pragma unroll
      for (int r = 0; r < 16; ++r) {
        int row = (r & 3) + 8 * (r >> 2) + 4 * hi;
        atomicAdd(&ob[(size_t)row * OUTD + l5], dacc[r]);
      }
    }

    __syncthreads();   // B3: publishes xlds; drains decode atomics (self only)
  }

  // final flag for the tail decoder (h_511 stores were acked pre-sub-flag)
  if (tid == 0) stflag(ffl + ct, (unsigned)TT);

  // ---- tail: decode h_511 -> out[255] (duty group 7; h_511 lives in hb0) ----
  if ((ct >> 2) == 7) {
    waitflags(ffl, (unsigned)TT, lane);
    const int ont = ct & 3;
    bf16x8 hreg[12];
    {
      const u64 hrow = (u64)(hb0 + (size_t)(b0 + l5) * HID + w * 192 + hi * 8);
      HLOADS();
    }
    VMWAIT(0);
    f32x16 dacc = ZERO16;
    #pragma unroll
    for (int t = 0; t < 12; ++t) dacc = MFMA32(hreg[t], Dreg[t], dacc);
    float* ob = out + ((size_t)255 * BB + b0) * OUTD + ont * 32;
    #pragma unroll
    for (int r = 0; r < 16; ++r) {
      int row = (r & 3) + 8 * (r >> 2) + 4 * hi;
      atomicAdd(&ob[(size_t)row * OUTD + l5], dacc[r]);
    }
  }
}

extern "C" void kernel_launch(void* const* d_in, const int* in_sizes, int n_in,
                              void* d_out, int out_size, void* d_ws, size_t ws_size,
                              hipStream_t stream) {
  (void)in_sizes; (void)n_in; (void)out_size; (void)ws_size;
  const float* seq   = (const float*)d_in[0];
  const float* W_ih  = (const float*)d_in[1];
  const float* W_hh  = (const float*)d_in[2];
  const float* b_ih  = (const float*)d_in[3];
  const float* b_hh  = (const float*)d_in[4];
  const float* W_dec = (const float*)d_in[5];
  const float* b_dec = (const float*)d_in[6];
  float* out = (float*)d_out;

  // workspace layout (~6.8 MB, all offsets 16B-aligned)
  u16* Wpack  = (u16*)d_ws;                         // 32*3*58*512 bf16
  u16* Wdpack = Wpack + 32 * 3 * KS_TOT * 512;      // 98,304 bf16
  u16* h0     = Wdpack + 4 * 48 * 512;              // 256*768 bf16
  u16* h1     = h0 + BB * HID;                      // 256*768 bf16
  float* biasg = (float*)(h1 + BB * HID);           // 3072 f32
  unsigned* sflags = (unsigned*)(biasg + 4 * HID);  // 1024 u32: [bt][ct][4] sub-flags
  unsigned* fflags = sflags + 1024;                 // 256 u32: [bt][ct] final flags

  prep_kernel<<<2048, 256, 0, stream>>>(W_ih, W_hh, b_ih, b_hh, W_dec, b_dec,
                                        Wpack, Wdpack, biasg, h0, sflags, out);
  lstm_persist<<<256, 256, 0, stream>>>(seq, Wpack, Wdpack, biasg,
                                        h0, h1, sflags, fflags, out);
}

// Round 6
// 2882.732 us; speedup vs baseline: 2.2514x; 1.0004x over previous
//
#include <hip/hip_runtime.h>
#include <cstdint>
#include <cstddef>

// ---- problem constants ----
#define TT 512
#define BB 256
#define HID 768
#define INDIM 129
#define OUTD 128
#define KS_TOT 58   // 48 recurrent + 10 input ksteps of 16
#define KS_REC 48
#define XSTR 168    // xlds row stride (bf16)
#define GSTR 100    // gbuf row stride (f32), 16B-aligned
#define DSTR 36     // dbuf row stride (f32): 144B rows, 16B-aligned, bank-spread

typedef __attribute__((ext_vector_type(8))) short bf16x8;
typedef __attribute__((ext_vector_type(4))) float f32x4;
typedef __attribute__((ext_vector_type(16))) float f32x16;
typedef unsigned short u16;
typedef unsigned long long u64;

#define MFMA32(A, B, C) __builtin_amdgcn_mfma_f32_32x32x16_bf16(A, B, C, 0, 0, 0)
#define ZERO16 {0.f,0.f,0.f,0.f,0.f,0.f,0.f,0.f,0.f,0.f,0.f,0.f,0.f,0.f,0.f,0.f}

__device__ __forceinline__ u16 f2bf(float f) {
  union { float f; unsigned u; } v; v.f = f;
  unsigned u = v.u;
  u += 0x7fffu + ((u >> 16) & 1u);   // RNE
  return (u16)(u >> 16);
}
__device__ __forceinline__ float sigm(float x) { return 1.0f / (1.0f + __expf(-x)); }
__device__ __forceinline__ float tanh_fast(float x) { return 2.0f / (1.0f + __expf(-2.0f * x)) - 1.0f; }

// ---------------- prep ----------------
__global__ __launch_bounds__(256) void prep_kernel(
    const float* __restrict__ W_ih, const float* __restrict__ W_hh,
    const float* __restrict__ b_ih, const float* __restrict__ b_hh,
    const float* __restrict__ W_dec, const float* __restrict__ b_dec,
    u16* __restrict__ Wpack, u16* __restrict__ Wdpack,
    float* __restrict__ biasg, u16* __restrict__ h0,
    unsigned* __restrict__ flags, float* __restrict__ out) {
  (void)b_dec; (void)out;   // out no longer pre-initialized (plain exclusive stores)
  const int stride = blockDim.x * gridDim.x;
  const int i0 = blockIdx.x * blockDim.x + threadIdx.x;

  // Wpack[ct][nt][ks][lane][8]: B-frag for mfma_32x32x16 (n=lane&31, k=(lane>>5)*8+jj)
  for (int i = i0; i < 32 * 3 * KS_TOT * 512; i += stride) {
    int jj = i & 7, lane = (i >> 3) & 63, r = i >> 9;
    int ks = r % KS_TOT; int r2 = r / KS_TOT;
    int nt = r2 % 3, ct = r2 / 3;
    int p = nt * 32 + (lane & 31);          // packed gate-col 0..95
    int g = p / 24, j = p - g * 24;
    int row = g * HID + ct * 24 + j;        // W gate-row
    int kh = (lane >> 5) * 8 + jj;
    float v;
    if (ks < KS_REC) v = W_hh[(size_t)row * HID + ks * 16 + kh];
    else { int d = (ks - KS_REC) * 16 + kh; v = (d < INDIM) ? W_ih[(size_t)row * INDIM + d] : 0.f; }
    Wpack[i] = f2bf(v);
  }
  // Wdpack[ont][ks][lane][8]
  for (int i = i0; i < 4 * 48 * 512; i += stride) {
    int jj = i & 7, lane = (i >> 3) & 63, r = i >> 9;
    int ks = r % 48, nt = r / 48;
    int orow = nt * 32 + (lane & 31);
    int k = ks * 16 + (lane >> 5) * 8 + jj;
    Wdpack[i] = f2bf(W_dec[(size_t)orow * HID + k]);
  }
  for (int i = i0; i < 4 * HID; i += stride) biasg[i] = b_ih[i] + b_hh[i];
  for (int i = i0; i < BB * HID; i += stride) h0[i] = (u16)0;
  // zero sflags(1024) + fflags(256)
  for (int i = i0; i < 1280; i += stride) flags[i] = 0u;
}

// ---------------- persistent LSTM ----------------
// Full-group wait (tail only)
__device__ __forceinline__ void waitflags(unsigned* fl, unsigned target, int lane) {
  for (;;) {
    unsigned v = __hip_atomic_load(&fl[lane & 31], __ATOMIC_RELAXED, __HIP_MEMORY_SCOPE_AGENT);
    if (__all((int)(v >= target))) break;
    __builtin_amdgcn_s_sleep(1);
  }
}
// Poll load: fused issue+wait inside ONE asm block (safe: no async register
// lifetime visible to the compiler — the R1-proven pattern).
__device__ __forceinline__ unsigned flagld(const unsigned* p) {
  unsigned v; u64 a = (u64)p;
  asm volatile("global_load_dword %0, %1, off sc0 sc1\n\ts_waitcnt vmcnt(0)"
               : "=v"(v) : "v"(a) : "memory");
  return v;
}
__device__ __forceinline__ void stflag(unsigned* p, unsigned v) {
  u64 a = (u64)p;
  asm volatile("global_store_dword %0, %1, off sc0 sc1" :: "v"(a), "v"(v) : "memory");
}

// Direct-to-register device-coherent 16B loads of MFMA A-frags (R1-proven).
// hreg is consumed after VMWAIT within the SAME iteration — no backedge
// crossing of in-flight asm destinations (R3/R4 lesson).
#define HLD(i, off) asm volatile( \
    "global_load_dwordx4 %0, %1, off offset:" #off " sc0 sc1" \
    : "=v"(hreg[i]) : "v"(hrow) : "memory")
#define HLOADS() do { HLD(0,0); HLD(1,32); HLD(2,64); HLD(3,96); \
    HLD(4,128); HLD(5,160); HLD(6,192); HLD(7,224); \
    HLD(8,256); HLD(9,288); HLD(10,320); HLD(11,352); } while (0)

#define VMWAIT(n) do { asm volatile("s_waitcnt vmcnt(" #n ")" ::: "memory"); \
    __builtin_amdgcn_sched_barrier(0); } while (0)

__global__ __launch_bounds__(256, 1) void lstm_persist(
    const float* __restrict__ seq, const u16* __restrict__ Wpack,
    const u16* __restrict__ Wdpack, const float* __restrict__ biasg,
    const float* __restrict__ b_dec,
    u16* __restrict__ hb0, u16* __restrict__ hb1,
    unsigned* __restrict__ sflags, unsigned* __restrict__ fflags,
    float* __restrict__ out) {
  __shared__ float gbuf[4][32 * GSTR];   // 51,200 B: gate partials
  __shared__ float dbuf[4][32 * DSTR];   // 18,432 B: decode K-partials (atomic-free)
  __shared__ u16 xlds[32 * XSTR];        // 10,752 B
  __shared__ float biasl[96];            // total ~81 KB: still 1 WG/CU

  const int tid = threadIdx.x;
  const int w = tid >> 6;
  const int lane = tid & 63;
  const int l5 = lane & 31;
  const int hi = lane >> 5;
  const int bid = blockIdx.x;
  const int bt = bid >> 5;               // 0..7  batch tile (32 rows)
  const int ct = bid & 31;               // 0..31 h-col tile (24 h-cols / 96 gate-cols)
  const int b0 = bt * 32;
  unsigned* sfl = sflags + bt * 128;     // [ct][4] per-cell-wave sub-flags
  unsigned* ffl = fflags + bt * 32;      // [ct] final flags (tail only)

  // one-time LDS init
  for (int i = tid; i < 32 * 31; i += 256) {      // zero x pad cols 129..159
    int r = i / 31, d = INDIM + i - r * 31;
    xlds[r * XSTR + d] = (u16)0;
  }
  if (tid < 96) biasl[tid] = biasg[(tid / 24) * HID + ct * 24 + (tid % 24)];

  // ---- recurrent-B fragments in registers: wave w owns rec ksteps w*12..w*12+11 ----
  bf16x8 Breg[3][12];
  #pragma unroll
  for (int t = 0; t < 12; ++t)
    #pragma unroll
    for (int nt = 0; nt < 3; ++nt)
      Breg[nt][t] = *(const bf16x8*)(Wpack +
          (((size_t)(ct * 3 + nt)) * KS_TOT + (w * 12 + t)) * 512 + (size_t)lane * 8);

  const int icnt = (w < 2) ? 3 : 2;              // input ksteps: 3/3/2/2
  const int ioff = (w <= 2) ? w * 3 : 8;
  bf16x8 Bireg[3][3] = {};
  #pragma unroll
  for (int u = 0; u < 3; ++u)
    if (u < icnt) {
      #pragma unroll
      for (int nt = 0; nt < 3; ++nt)
        Bireg[u][nt] = *(const bf16x8*)(Wpack +
            (((size_t)(ct * 3 + nt)) * KS_TOT + KS_REC + ioff + u) * 512 + (size_t)lane * 8);
    }

  // decoder B-fragments in registers (ont = ct&3 fixed per WG; in-loop + tail)
  bf16x8 Dreg[12];
  #pragma unroll
  for (int t = 0; t < 12; ++t)
    Dreg[t] = *(const bf16x8*)(Wdpack +
        (((size_t)(ct & 3) * 48 + w * 12 + t) * 64 + lane) * 8);

  // stage x_0
  {
    const float* xs = seq + (size_t)b0 * INDIM;
    for (int i = tid; i < 32 * INDIM; i += 256) {
      int r = i / INDIM, d = i - r * INDIM;
      xlds[r * XSTR + d] = f2bf(xs[i]);
    }
  }

  // cell state: thread-private (threads 0..191 own (row=tid/6, colgrp=tid%6) forever)
  float creg[4] = {0.f, 0.f, 0.f, 0.f};
  const int cr = tid / 6, cg = tid - (tid / 6) * 6;
  // wave w consumes h cols [w*192,+192) <- producers ct'=8w..8w+7, cell-waves 0..2:
  const unsigned* sfp = sfl + ((lane < 24) ? ((8 * w + lane / 3) * 4 + (lane % 3))
                                           : (8 * w) * 4);
  // decode sum-phase indexing: thread -> (row, 4-col group) of the 32x32 out tile
  const int srow = tid >> 3, sc4 = (tid & 7) * 4;
  const int ont = ct & 3;

  __syncthreads();   // x_0 + pads + biasl ready

  for (int s = 0; s < TT; ++s) {
    const u16* hbprev = (s & 1) ? hb1 : hb0;
    u16* hbnext       = (s & 1) ? hb0 : hb1;
    const bool duty = (s >= 257) && ((ct >> 2) == ((s - 257) & 7));

    // ---- input projection slice #0 BEFORE poll: fills the flag-visibility
    // window (xlds is valid from prev B3) ----
    f32x16 acc[3] = {ZERO16, ZERO16, ZERO16};
    {
      int kk = ioff;
      bf16x8 a = *(const bf16x8*)(xlds + l5 * XSTR + kk * 16 + hi * 8);
      acc[0] = MFMA32(a, Bireg[0][0], acc[0]);
      acc[1] = MFMA32(a, Bireg[0][1], acc[1]);
      acc[2] = MFMA32(a, Bireg[0][2], acc[2]);
    }

    // ---- poll (queue is empty: x/decode drained at B2/B3 last step) ----
    for (;;) {
      unsigned v = flagld(sfp);
      if (__all((int)(v >= (unsigned)s))) break;
      __builtin_amdgcn_s_sleep(1);
    }

    // ---- h_{s-1} direct to registers: issue immediately after flag confirm ----
    bf16x8 hreg[12];
    {
      const u64 hrow = (u64)(hbprev + (size_t)(b0 + l5) * HID + w * 192 + hi * 8);
      HLOADS();
    }

    // ---- remaining input-proj slices UNDER the h RT ----
    #pragma unroll
    for (int u = 1; u < 3; ++u)
      if (u < icnt) {
        int kk = ioff + u;
        bf16x8 a = *(const bf16x8*)(xlds + l5 * XSTR + kk * 16 + hi * 8);
        acc[0] = MFMA32(a, Bireg[u][0], acc[0]);
        acc[1] = MFMA32(a, Bireg[u][1], acc[1]);
        acc[2] = MFMA32(a, Bireg[u][2], acc[2]);
      }

    // ---- recurrent MFMA: queue is h-only -> simple counted waits ----
    VMWAIT(6);          // oldest 6 h loads retired (in-order retirement)
    #pragma unroll
    for (int t = 0; t < 6; ++t) {
      acc[0] = MFMA32(hreg[t], Breg[0][t], acc[0]);
      acc[1] = MFMA32(hreg[t], Breg[1][t], acc[1]);
      acc[2] = MFMA32(hreg[t], Breg[2][t], acc[2]);
    }
    VMWAIT(0);
    #pragma unroll
    for (int t = 6; t < 12; ++t) {
      acc[0] = MFMA32(hreg[t], Breg[0][t], acc[0]);
      acc[1] = MFMA32(hreg[t], Breg[1][t], acc[1]);
      acc[2] = MFMA32(hreg[t], Breg[2][t], acc[2]);
    }

    // ---- x_{s+1} prefetch issue AFTER h waits (drains at B2) ----
    float xf[17];
    if (s + 1 < TT) {
      const float* xs = seq + ((size_t)(s + 1) * BB + b0) * INDIM;
      #pragma unroll
      for (int k = 0; k < 17; ++k) {
        int i = tid + k * 256;
        xf[k] = (i < 32 * INDIM) ? xs[i] : 0.f;
      }
    }

    // ---- write gate partials ----
    {
      float* gbw = &gbuf[w][0];
      #pragma unroll
      for (int nt = 0; nt < 3; ++nt)
        #pragma unroll
        for (int r = 0; r < 16; ++r) {
          int row = (r & 3) + 8 * (r >> 2) + 4 * hi;
          gbw[row * GSTR + nt * 32 + l5] = acc[nt][r];
        }
    }

    __syncthreads();   // B2: partials ready; drains x loads; queue now empty

    // ---- cell update: threads 0..191 (waves 0..2), 4 cells each, c in regs.
    // Each cell wave drains ITS OWN h stores and posts its sub-flag BEFORE
    // the xlds write / decode / B3 — the handoff leaves the WG here. ----
    if (tid < 192) {
      float gv4[4][4];
      #pragma unroll
      for (int g = 0; g < 4; ++g) {
        f32x4 v = *(f32x4*)&gbuf[0][cr * GSTR + g * 24 + cg * 4];
        #pragma unroll
        for (int w2 = 1; w2 < 4; ++w2)
          v += *(f32x4*)&gbuf[w2][cr * GSTR + g * 24 + cg * 4];
        #pragma unroll
        for (int e = 0; e < 4; ++e) gv4[g][e] = v[e] + biasl[g * 24 + cg * 4 + e];
      }
      u64 pack = 0;
      #pragma unroll
      for (int e = 0; e < 4; ++e) {
        float iv = sigm(gv4[0][e]), fv2 = sigm(gv4[1][e]);
        float gg = tanh_fast(gv4[2][e]), ov = sigm(gv4[3][e]);
        float cn = fv2 * creg[e] + iv * gg;
        creg[e] = cn;
        pack |= (u64)f2bf(ov * tanh_fast(cn)) << (16 * e);
      }
      __hip_atomic_store((u64*)hbnext + ((size_t)(b0 + cr) * HID + ct * 24 + cg * 4) / 4,
                         pack, __ATOMIC_RELAXED, __HIP_MEMORY_SCOPE_AGENT);
      // queue holds ONLY this wave's h store (B2 drained everything else):
      // ack it at the coherence point, then post this wave's sub-flag.
      asm volatile("s_waitcnt vmcnt(0)" ::: "memory");
      __builtin_amdgcn_sched_barrier(0);
      if (lane == 0) stflag(sfl + ct * 4 + w, (unsigned)(s + 1));
    }

    // ---- write x_{s+1} to xlds (cell waves after their sub-flag; wave 3 now) ----
    if (s + 1 < TT) {
      #pragma unroll
      for (int k = 0; k < 17; ++k) {
        int i = tid + k * 256;
        if (i < 32 * INDIM) {
          int r = i / INDIM, d = i - r * INDIM;
          xlds[r * XSTR + d] = f2bf(xf[k]);
        }
      }
    }

    // ---- fused decode K-partials -> dbuf (atomic-free; separate buffer so
    // no race with gbuf cell reads; B3 publishes; dbuf not rewritten for 8
    // barrier-separated steps) ----
    if (duty) {
      f32x16 dacc = ZERO16;
      #pragma unroll
      for (int t = 0; t < 12; ++t) dacc = MFMA32(hreg[t], Dreg[t], dacc);
      float* db = &dbuf[w][0];
      #pragma unroll
      for (int r = 0; r < 16; ++r) {
        int row = (r & 3) + 8 * (r >> 2) + 4 * hi;
        db[row * DSTR + l5] = dacc[r];
      }
    }

    __syncthreads();   // B3: publishes xlds + dbuf

    // ---- duty sum phase: 4 K-partials + bias -> PLAIN cached stores (no LLC
    // RMW interference with other WGs' polls/h-loads) ----
    if (duty) {
      const int t0 = s - 257;
      f32x4 v = *(f32x4*)&dbuf[0][srow * DSTR + sc4];
      #pragma unroll
      for (int w2 = 1; w2 < 4; ++w2)
        v += *(f32x4*)&dbuf[w2][srow * DSTR + sc4];
      #pragma unroll
      for (int e = 0; e < 4; ++e) v[e] += b_dec[ont * 32 + sc4 + e];
      *(f32x4*)&out[((size_t)t0 * BB + b0 + srow) * OUTD + ont * 32 + sc4] = v;
    }
  }

  // final flag for the tail decoder (h_511 stores were acked pre-sub-flag)
  if (tid == 0) stflag(ffl + ct, (unsigned)TT);

  // ---- tail: decode h_511 -> out[255] (duty group 7; h_511 lives in hb0) ----
  if ((ct >> 2) == 7) {
    waitflags(ffl, (unsigned)TT, lane);
    bf16x8 hreg[12];
    {
      const u64 hrow = (u64)(hb0 + (size_t)(b0 + l5) * HID + w * 192 + hi * 8);
      HLOADS();
    }
    VMWAIT(0);
    f32x16 dacc = ZERO16;
    #pragma unroll
    for (int t = 0; t < 12; ++t) dacc = MFMA32(hreg[t], Dreg[t], dacc);
    float* db = &dbuf[w][0];
    #pragma unroll
    for (int r = 0; r < 16; ++r) {
      int row = (r & 3) + 8 * (r >> 2) + 4 * hi;
      db[row * DSTR + l5] = dacc[r];
    }
    __syncthreads();
    f32x4 v = *(f32x4*)&dbuf[0][srow * DSTR + sc4];
    #pragma unroll
    for (int w2 = 1; w2 < 4; ++w2)
      v += *(f32x4*)&dbuf[w2][srow * DSTR + sc4];
    #pragma unroll
    for (int e = 0; e < 4; ++e) v[e] += b_dec[ont * 32 + sc4 + e];
    *(f32x4*)&out[((size_t)255 * BB + b0 + srow) * OUTD + ont * 32 + sc4] = v;
  }
}

extern "C" void kernel_launch(void* const* d_in, const int* in_sizes, int n_in,
                              void* d_out, int out_size, void* d_ws, size_t ws_size,
                              hipStream_t stream) {
  (void)in_sizes; (void)n_in; (void)out_size; (void)ws_size;
  const float* seq   = (const float*)d_in[0];
  const float* W_ih  = (const float*)d_in[1];
  const float* W_hh  = (const float*)d_in[2];
  const float* b_ih  = (const float*)d_in[3];
  const float* b_hh  = (const float*)d_in[4];
  const float* W_dec = (const float*)d_in[5];
  const float* b_dec = (const float*)d_in[6];
  float* out = (float*)d_out;

  // workspace layout (~6.8 MB, all offsets 16B-aligned)
  u16* Wpack  = (u16*)d_ws;                         // 32*3*58*512 bf16
  u16* Wdpack = Wpack + 32 * 3 * KS_TOT * 512;      // 98,304 bf16
  u16* h0     = Wdpack + 4 * 48 * 512;              // 256*768 bf16
  u16* h1     = h0 + BB * HID;                      // 256*768 bf16
  float* biasg = (float*)(h1 + BB * HID);           // 3072 f32
  unsigned* sflags = (unsigned*)(biasg + 4 * HID);  // 1024 u32: [bt][ct][4] sub-flags
  unsigned* fflags = sflags + 1024;                 // 256 u32: [bt][ct] final flags

  prep_kernel<<<2048, 256, 0, stream>>>(W_ih, W_hh, b_ih, b_hh, W_dec, b_dec,
                                        Wpack, Wdpack, biasg, h0, sflags, out);
  lstm_persist<<<256, 256, 0, stream>>>(seq, Wpack, Wdpack, biasg, b_dec,
                                        h0, h1, sflags, fflags, out);
}